// Round 2
// baseline (441.998 us; speedup 1.0000x reference)
//
#include <hip/hip_runtime.h>
#include <hip/hip_fp16.h>
#include <math.h>

typedef _Float16 f16;
typedef unsigned int u32;
typedef _Float16 f16x8 __attribute__((ext_vector_type(8)));
typedef _Float16 f16x4 __attribute__((ext_vector_type(4)));
typedef float    f32x4 __attribute__((ext_vector_type(4)));

constexpr int LEN  = 512;   // sequence length L
constexpr int HID  = 512;   // hidden H
constexpr int BATCH = 64;

#define BM 128
#define BN 128
#define BK 64

// ---- async global->LDS, 16B per lane. lds ptr must be wave-uniform. ----
__device__ __forceinline__ void gload16(const f16* g, f16* l) {
    __builtin_amdgcn_global_load_lds((const __attribute__((address_space(1))) u32*)g,
                                     (__attribute__((address_space(3))) u32*)l,
                                     16, 0, 0);
}

// ---- core bt-GEMM: C[128x128] += A[128xK] * B[128xK]^T, fp16 in, fp32 acc ----
// A, B already offset to tile start. lda/ldb in elements.
__device__ __forceinline__ void gemm_core(const f16* __restrict__ A, int lda,
                                          const f16* __restrict__ Bm, int ldb,
                                          int ksteps,
                                          f16* ldsA, f16* ldsB,
                                          f32x4 acc[4][4])
{
    const int tid  = threadIdx.x;
    const int lane = tid & 63;
    const int wv   = tid >> 6;
    const int wr   = wv >> 1, wc = wv & 1;
    const int mf   = lane & 15;
    const int kf   = (lane >> 4) * 8;

    for (int r = 0; r < 4; ++r)
        for (int c = 0; c < 4; ++c)
            acc[r][c] = (f32x4){0.f, 0.f, 0.f, 0.f};

    for (int kt = 0; kt < ksteps; ++kt) {
        const int k0 = kt * BK;
        // stage 128x64 fp16 tiles (16KB each): 1024 16B chunks, 4 per thread
        #pragma unroll
        for (int j = 0; j < 4; ++j) {
            const int cb  = j * 256 + wv * 64;   // wave-uniform chunk base
            const int c   = cb + lane;
            const int row = c >> 3;
            const int col = (c & 7) << 3;
            gload16(A  + (size_t)row * lda + (k0 + col), ldsA + cb * 8);
            gload16(Bm + (size_t)row * ldb + (k0 + col), ldsB + cb * 8);
        }
        __syncthreads();
        #pragma unroll
        for (int kk = 0; kk < BK; kk += 32) {
            f16x8 af[4], bf[4];
            #pragma unroll
            for (int r = 0; r < 4; ++r) {
                af[r] = *(const f16x8*)(ldsA + (wr * 64 + r * 16 + mf) * BK + kk + kf);
                bf[r] = *(const f16x8*)(ldsB + (wc * 64 + r * 16 + mf) * BK + kk + kf);
            }
            #pragma unroll
            for (int r = 0; r < 4; ++r)
                #pragma unroll
                for (int c = 0; c < 4; ++c)
                    acc[r][c] = __builtin_amdgcn_mfma_f32_16x16x32_f16(af[r], bf[c], acc[r][c], 0, 0, 0);
        }
        __syncthreads();
    }
}

// C/D layout (16x16x32): col = lane&15, row = (lane>>4)*4 + reg   [m89-verified]
#define EPILOGUE_IDX() \
    const int lane = threadIdx.x & 63, wv_ = threadIdx.x >> 6;   \
    const int wr = wv_ >> 1, wc = wv_ & 1;                       \
    const int c0 = lane & 15, r0 = (lane >> 4) * 4;

// ---- GEMM + silu -> fp16 ----
__global__ __launch_bounds__(256) void k_gemm_silu(const f16* __restrict__ A,
                                                   const f16* __restrict__ W,
                                                   f16* __restrict__ out)
{
    __shared__ f16 ldsA[BM * BK], ldsB[BN * BK];
    f32x4 acc[4][4];
    const int tn = blockIdx.x, tm = blockIdx.y;
    gemm_core(A + (size_t)tm * BM * HID, HID, W + (size_t)tn * BN * HID, HID,
              HID / BK, ldsA, ldsB, acc);
    EPILOGUE_IDX();
    #pragma unroll
    for (int r = 0; r < 4; ++r)
        #pragma unroll
        for (int c = 0; c < 4; ++c) {
            const int gj = tn * BN + wc * 64 + c * 16 + c0;
            #pragma unroll
            for (int i = 0; i < 4; ++i) {
                const int gi = tm * BM + wr * 64 + r * 16 + r0 + i;
                const float v = acc[r][c][i];
                const float s = v / (1.f + expf(-v));
                out[(size_t)gi * HID + gj] = (f16)s;
            }
        }
}

// ---- GEMM + offset-scale, x1024 range lift -> fp16 ----
__global__ __launch_bounds__(256) void k_gemm_os(const f16* __restrict__ A,
                                                 const f16* __restrict__ W,
                                                 const float* __restrict__ gamma,
                                                 const float* __restrict__ beta,
                                                 f16* __restrict__ out)
{
    __shared__ f16 ldsA[BM * BK], ldsB[BN * BK];
    f32x4 acc[4][4];
    const int tn = blockIdx.x, tm = blockIdx.y;
    gemm_core(A + (size_t)tm * BM * HID, HID, W + (size_t)tn * BN * HID, HID,
              HID / BK, ldsA, ldsB, acc);
    EPILOGUE_IDX();
    #pragma unroll
    for (int r = 0; r < 4; ++r)
        #pragma unroll
        for (int c = 0; c < 4; ++c) {
            const int gj = tn * BN + wc * 64 + c * 16 + c0;
            const float g = gamma[gj], b = beta[gj];
            #pragma unroll
            for (int i = 0; i < 4; ++i) {
                const int gi = tm * BM + wr * 64 + r * 16 + r0 + i;
                const float v = acc[r][c][i] * g + b;
                out[(size_t)gi * HID + gj] = (f16)(v * 1024.f);
            }
        }
}

// ---- batched q@k^T + mask + smask + relu^2 -> p (fp16) ----
__global__ __launch_bounds__(256) void k_qk(const f16* __restrict__ q,
                                            const f16* __restrict__ kmat,
                                            const int* __restrict__ mask,
                                            const float* __restrict__ smask,
                                            f16* __restrict__ p)
{
    const int mt = blockIdx.x, lt = blockIdx.y, b = blockIdx.z;
    if (mt > lt) return;   // strictly-upper tiles are all-masked; never read downstream
    __shared__ f16 ldsA[BM * BK], ldsB[BN * BK];
    f32x4 acc[4][4];
    const size_t boff = (size_t)b * LEN * HID;
    gemm_core(q + boff + (size_t)lt * BM * HID, HID,
              kmat + boff + (size_t)mt * BN * HID, HID,
              HID / BK, ldsA, ldsB, acc);
    EPILOGUE_IDX();
    #pragma unroll
    for (int r = 0; r < 4; ++r)
        #pragma unroll
        for (int c = 0; c < 4; ++c) {
            const int m = mt * BN + wc * 64 + c * 16 + c0;
            const int keepcol = mask[b * LEN + m];
            #pragma unroll
            for (int i = 0; i < 4; ++i) {
                const int l = lt * BM + wr * 64 + r * 16 + r0 + i;
                const bool keep = (l == m) || ((m <= l) && (keepcol != 0));
                float v = keep ? acc[r][c][i] * smask[l * LEN + m] : 0.f;
                v = fmaxf(v, 0.f);
                p[(size_t)b * LEN * LEN + (size_t)l * LEN + m] = (f16)(v * v);
            }
        }
}

// ---- batched p@v (v pre-transposed) -> out f32, causal K truncation ----
__global__ __launch_bounds__(256) void k_pv(const f16* __restrict__ p,
                                            const f16* __restrict__ vt,
                                            float* __restrict__ out)
{
    const int ht = blockIdx.x, lt = blockIdx.y, b = blockIdx.z;
    __shared__ f16 ldsA[BM * BK], ldsB[BN * BK];
    f32x4 acc[4][4];
    gemm_core(p + (size_t)b * LEN * LEN + (size_t)lt * BM * LEN, LEN,
              vt + (size_t)b * HID * LEN + (size_t)ht * BN * LEN, LEN,
              (lt + 1) * BM / BK, ldsA, ldsB, acc);
    EPILOGUE_IDX();
    // undo q,k 2^10 scales (2^20 -> squared = 2^40) and /(L*H)=2^18 : 2^-58
    const float SCALE = 3.4694469519536142e-18f;  // 2^-58, exact
    #pragma unroll
    for (int r = 0; r < 4; ++r)
        #pragma unroll
        for (int c = 0; c < 4; ++c) {
            const int h = ht * BN + wc * 64 + c * 16 + c0;
            #pragma unroll
            for (int i = 0; i < 4; ++i) {
                const int l = lt * BM + wr * 64 + r * 16 + r0 + i;
                out[(size_t)b * LEN * HID + (size_t)l * HID + h] = acc[r][c][i] * SCALE;
            }
        }
}

// ---- gather item_emb[positives] + pos_emb -> fp16 x ----
__global__ __launch_bounds__(256) void k_gather(const int* __restrict__ pos,
                                                const float* __restrict__ item_emb,
                                                const float* __restrict__ pos_emb,
                                                f16* __restrict__ x)
{
    const int t = blockIdx.x * 256 + threadIdx.x;
    const int i = t >> 7;          // row in [0, B*L)
    const int c = t & 127;         // float4 column
    const int l = i & (LEN - 1);
    const int item = pos[i];
    const float4 a  = ((const float4*)(item_emb + (size_t)item * HID))[c];
    const float4 b4 = ((const float4*)(pos_emb + (size_t)l * HID))[c];
    f16x4 o = { (f16)(a.x + b4.x), (f16)(a.y + b4.y),
                (f16)(a.z + b4.z), (f16)(a.w + b4.w) };
    *(f16x4*)(x + (size_t)t * 4) = o;
}

// ---- fp32 -> fp16 weight cast ----
__global__ __launch_bounds__(256) void k_f2h(const float* __restrict__ s, f16* __restrict__ d)
{
    const int t = blockIdx.x * 256 + threadIdx.x;
    const float4 v = ((const float4*)s)[t];
    f16x4 o = { (f16)v.x, (f16)v.y, (f16)v.z, (f16)v.w };
    *(f16x4*)(d + (size_t)t * 4) = o;
}

// ---- gumbel-sigmoid sparse mask (fp32) ----
__global__ __launch_bounds__(256) void k_smask(const float* __restrict__ w,
                                               const float* __restrict__ g,
                                               float* __restrict__ s)
{
    const int t = blockIdx.x * 256 + threadIdx.x;
    const float wv = w[t];
    const float x = (logf(wv / (1.f - wv)) + g[t]) / 0.2f;
    s[t] = 1.f / (1.f + expf(-x));
}

// ---- batched 512x512 fp16 transpose: vt[b][h][m] = v[b][m][h] ----
__global__ __launch_bounds__(256) void k_transpose(const f16* __restrict__ v,
                                                   f16* __restrict__ vt)
{
    __shared__ f16 tile[64][65];
    const int b = blockIdx.z;
    const int h0 = blockIdx.x * 64, m0 = blockIdx.y * 64;
    const int tid = threadIdx.x;
    #pragma unroll
    for (int ph = 0; ph < 2; ++ph) {
        const int cc = ph * 256 + tid;
        const int row = cc >> 3, col = (cc & 7) << 3;
        const f16x8 val = *(const f16x8*)(v + ((size_t)b * LEN + m0 + row) * HID + h0 + col);
        #pragma unroll
        for (int j = 0; j < 8; ++j) tile[row][col + j] = val[j];
    }
    __syncthreads();
    #pragma unroll
    for (int ph = 0; ph < 2; ++ph) {
        const int cc = ph * 256 + tid;
        const int hh = cc >> 3, mb = (cc & 7) << 3;
        f16x8 o;
        #pragma unroll
        for (int j = 0; j < 8; ++j) o[j] = tile[mb + j][hh];
        *(f16x8*)(vt + ((size_t)b * HID + h0 + hh) * LEN + m0 + mb) = o;
    }
}

extern "C" void kernel_launch(void* const* d_in, const int* in_sizes, int n_in,
                              void* d_out, int out_size, void* d_ws, size_t ws_size,
                              hipStream_t stream)
{
    const int*   positives = (const int*)  d_in[0];
    const int*   mask      = (const int*)  d_in[1];
    const float* item_emb  = (const float*)d_in[2];
    const float* pos_emb   = (const float*)d_in[3];
    const float* Wz        = (const float*)d_in[4];
    const float* Wv        = (const float*)d_in[5];
    const float* Wq        = (const float*)d_in[6];
    const float* Wk        = (const float*)d_in[7];
    const float* gamma_q   = (const float*)d_in[8];
    const float* beta_q    = (const float*)d_in[9];
    const float* gamma_k   = (const float*)d_in[10];
    const float* beta_k    = (const float*)d_in[11];
    const float* sparse_w  = (const float*)d_in[12];
    const float* gumbel    = (const float*)d_in[13];
    float* out = (float*)d_out;

    // workspace layout: 3 x 32MB fp16 + 4 x 0.5MB fp16 weights + 1MB smask = ~100MB
    char* ws = (char*)d_ws;
    const size_t BUFB = (size_t)BATCH * LEN * HID * sizeof(f16);  // 32 MB
    f16* buf0 = (f16*)ws;                // x  -> vt
    f16* buf1 = (f16*)(ws + BUFB);       // z
    f16* buf2 = (f16*)(ws + 2 * BUFB);   // v  -> p
    f16* Wzh  = (f16*)(ws + 3 * BUFB);
    f16* Wvh  = Wzh + LEN * HID;
    f16* Wqh  = Wvh + LEN * HID;
    f16* Wkh  = Wqh + LEN * HID;
    float* smask = (float*)(Wkh + LEN * HID);
    // q,k live in d_out (exactly 2 x 32MB fp16) until k_pv overwrites it
    f16* qh = (f16*)d_out;
    f16* kh = qh + (size_t)BATCH * LEN * HID;

    k_f2h<<<256, 256, 0, stream>>>(Wz, Wzh);
    k_f2h<<<256, 256, 0, stream>>>(Wv, Wvh);
    k_f2h<<<256, 256, 0, stream>>>(Wq, Wqh);
    k_f2h<<<256, 256, 0, stream>>>(Wk, Wkh);
    k_smask<<<1024, 256, 0, stream>>>(sparse_w, gumbel, smask);
    k_gather<<<16384, 256, 0, stream>>>(positives, item_emb, pos_emb, buf0);

    const dim3 gBig(HID / BN, (BATCH * LEN) / BM);   // (4, 256)
    k_gemm_silu<<<gBig, 256, 0, stream>>>(buf0, Wzh, buf1);                 // z
    k_gemm_silu<<<gBig, 256, 0, stream>>>(buf0, Wvh, buf2);                 // v
    k_transpose<<<dim3(8, 8, BATCH), 256, 0, stream>>>(buf2, buf0);         // vt (x dead)
    k_gemm_os<<<gBig, 256, 0, stream>>>(buf1, Wqh, gamma_q, beta_q, qh);    // q
    k_gemm_os<<<gBig, 256, 0, stream>>>(buf1, Wkh, gamma_k, beta_k, kh);    // k
    k_qk<<<dim3(4, 4, BATCH), 256, 0, stream>>>(qh, kh, mask, smask, buf2); // p (v dead)
    k_pv<<<dim3(4, 4, BATCH), 256, 0, stream>>>(buf2, buf0, out);           // out
}

// Round 3
// 412.544 us; speedup vs baseline: 1.0714x; 1.0714x over previous
//
#include <hip/hip_runtime.h>
#include <hip/hip_fp16.h>
#include <math.h>

typedef _Float16 f16;
typedef unsigned int u32;
typedef _Float16 f16x8 __attribute__((ext_vector_type(8)));
typedef _Float16 f16x4 __attribute__((ext_vector_type(4)));
typedef float    f32x4 __attribute__((ext_vector_type(4)));

constexpr int LEN  = 512;
constexpr int HID  = 512;
constexpr int BATCH = 64;

#define BM 128
#define BN 128
#define BK 64

// ---- async global->LDS, 16B per lane. lds ptr must be wave-uniform. ----
__device__ __forceinline__ void gload16(const f16* g, f16* l) {
    __builtin_amdgcn_global_load_lds((const __attribute__((address_space(1))) u32*)g,
                                     (__attribute__((address_space(3))) u32*)l,
                                     16, 0, 0);
}

// ---- core bt-GEMM: C[128x128] += A[128xK] * B[128xK]^T, fp16 in, fp32 acc ----
__device__ __forceinline__ void gemm_core(const f16* __restrict__ A, int lda,
                                          const f16* __restrict__ Bm, int ldb,
                                          int ksteps,
                                          f16* ldsA, f16* ldsB,
                                          f32x4 acc[4][4])
{
    const int tid  = threadIdx.x;
    const int lane = tid & 63;
    const int wv   = tid >> 6;
    const int wr   = wv >> 1, wc = wv & 1;
    const int mf   = lane & 15;
    const int kf   = (lane >> 4) * 8;

    for (int r = 0; r < 4; ++r)
        for (int c = 0; c < 4; ++c)
            acc[r][c] = (f32x4){0.f, 0.f, 0.f, 0.f};

    for (int kt = 0; kt < ksteps; ++kt) {
        const int k0 = kt * BK;
        #pragma unroll
        for (int j = 0; j < 4; ++j) {
            const int cb  = j * 256 + wv * 64;   // wave-uniform chunk base
            const int c   = cb + lane;
            const int row = c >> 3;
            const int col = (c & 7) << 3;
            gload16(A  + (size_t)row * lda + (k0 + col), ldsA + cb * 8);
            gload16(Bm + (size_t)row * ldb + (k0 + col), ldsB + cb * 8);
        }
        __syncthreads();
        #pragma unroll
        for (int kk = 0; kk < BK; kk += 32) {
            f16x8 af[4], bf[4];
            #pragma unroll
            for (int r = 0; r < 4; ++r) {
                af[r] = *(const f16x8*)(ldsA + (wr * 64 + r * 16 + mf) * BK + kk + kf);
                bf[r] = *(const f16x8*)(ldsB + (wc * 64 + r * 16 + mf) * BK + kk + kf);
            }
            #pragma unroll
            for (int r = 0; r < 4; ++r)
                #pragma unroll
                for (int c = 0; c < 4; ++c)
                    acc[r][c] = __builtin_amdgcn_mfma_f32_16x16x32_f16(af[r], bf[c], acc[r][c], 0, 0, 0);
        }
        __syncthreads();
    }
}

// C/D layout (16x16x32): col = lane&15, row = (lane>>4)*4 + reg   [m89-verified]
#define EPILOGUE_IDX() \
    const int lane = threadIdx.x & 63, wv_ = threadIdx.x >> 6;   \
    const int wr = wv_ >> 1, wc = wv_ & 1;                       \
    const int c0 = lane & 15, r0 = (lane >> 4) * 4;

// ---- vectorized f16 tile store: C-layout regs -> LDS -> coalesced f16x8 ----
// lds must be >= 128*128 f16 (32 KB). gemm_core's trailing barrier makes reuse safe.
__device__ __forceinline__ void store_tile_f16(f16* lds, const f16 vals[4][4][4],
                                               f16* __restrict__ gout, int ldo)
{
    const int tid = threadIdx.x;
    EPILOGUE_IDX();
    #pragma unroll
    for (int r = 0; r < 4; ++r)
        #pragma unroll
        for (int c = 0; c < 4; ++c)
            #pragma unroll
            for (int i = 0; i < 4; ++i) {
                const int lr = wr * 64 + r * 16 + r0 + i;
                const int lc = wc * 64 + c * 16 + c0;
                lds[lr * 128 + lc] = vals[r][c][i];
            }
    __syncthreads();
    #pragma unroll
    for (int ph = 0; ph < 8; ++ph) {
        const int row = ph * 16 + (tid >> 4);
        const int col = (tid & 15) * 8;
        *(f16x8*)(gout + (size_t)row * ldo + col) = *(const f16x8*)(lds + row * 128 + col);
    }
}

__device__ __forceinline__ float silu_f(float v) { return v / (1.f + expf(-v)); }

// ---- z = silu(x @ Wz^T) ----
__global__ __launch_bounds__(256) void k_zg(const f16* __restrict__ A,
                                            const f16* __restrict__ W,
                                            f16* __restrict__ out)
{
    __shared__ f16 lds[(BM + BN) * BK];
    f32x4 acc[4][4];
    const int tn = blockIdx.x, tm = blockIdx.y;
    gemm_core(A + (size_t)tm * BM * HID, HID, W + (size_t)tn * BN * HID, HID,
              HID / BK, lds, lds + BM * BK, acc);
    f16 vals[4][4][4];
    #pragma unroll
    for (int r = 0; r < 4; ++r)
        #pragma unroll
        for (int c = 0; c < 4; ++c)
            #pragma unroll
            for (int i = 0; i < 4; ++i)
                vals[r][c][i] = (f16)silu_f(acc[r][c][i]);
    store_tile_f16(lds, vals, out + (size_t)tm * BM * HID + tn * BN, HID);
}

// ---- fused v^T | q | k projections in one launch ----
// bid [0,1024):    vt[b][h][m] = silu(Wv_h . x_bm)   (transposed-v GEMM, no transpose kernel)
// bid [1024,2048): q = (z@Wq^T)*gamma_q+beta_q, x1024 lift
// bid [2048,3072): k likewise
__global__ __launch_bounds__(256) void k_vqk(const f16* __restrict__ x,
                                             const f16* __restrict__ z,
                                             const f16* __restrict__ Wvh,
                                             const f16* __restrict__ Wqh,
                                             const f16* __restrict__ Wkh,
                                             const float* __restrict__ gq,
                                             const float* __restrict__ bq,
                                             const float* __restrict__ gk,
                                             const float* __restrict__ bk,
                                             f16* __restrict__ vt,
                                             f16* __restrict__ qh,
                                             f16* __restrict__ kh)
{
    __shared__ f16 lds[(BM + BN) * BK];
    f32x4 acc[4][4];
    f16 vals[4][4][4];
    const int bid = blockIdx.x;
    if (bid < 1024) {
        const int ht = bid & 3, mt = (bid >> 2) & 3, b = bid >> 4;
        gemm_core(Wvh + (size_t)ht * BM * HID, HID,
                  x + ((size_t)b * LEN + mt * BN) * HID, HID,
                  HID / BK, lds, lds + BM * BK, acc);
        #pragma unroll
        for (int r = 0; r < 4; ++r)
            #pragma unroll
            for (int c = 0; c < 4; ++c)
                #pragma unroll
                for (int i = 0; i < 4; ++i)
                    vals[r][c][i] = (f16)silu_f(acc[r][c][i]);
        store_tile_f16(lds, vals,
                       vt + (size_t)b * LEN * HID + (size_t)ht * BM * LEN + mt * BN, LEN);
    } else {
        const bool isq = bid < 2048;
        const int l = bid - (isq ? 1024 : 2048);
        const int tn = l & 3, tm = l >> 2;
        const f16* W = isq ? Wqh : Wkh;
        const float* g = isq ? gq : gk;
        const float* be = isq ? bq : bk;
        f16* out = isq ? qh : kh;
        gemm_core(z + (size_t)tm * BM * HID, HID, W + (size_t)tn * BN * HID, HID,
                  HID / BK, lds, lds + BM * BK, acc);
        EPILOGUE_IDX();
        #pragma unroll
        for (int r = 0; r < 4; ++r)
            #pragma unroll
            for (int c = 0; c < 4; ++c) {
                const int gj = tn * BN + wc * 64 + c * 16 + c0;
                const float ga = g[gj], ba = be[gj];
                #pragma unroll
                for (int i = 0; i < 4; ++i)
                    vals[r][c][i] = (f16)((acc[r][c][i] * ga + ba) * 1024.f);
            }
        store_tile_f16(lds, vals, out + (size_t)tm * BM * HID + tn * BN, HID);
    }
}

// ---- batched q@k^T + mask + smask + relu^2 -> p (fp16), compact triangular grid ----
__constant__ int LT_TAB[10] = {0,1,1,2,2,2,3,3,3,3};
__constant__ int MT_TAB[10] = {0,0,1,0,1,2,0,1,2,3};

__global__ __launch_bounds__(256) void k_qk(const f16* __restrict__ q,
                                            const f16* __restrict__ kmat,
                                            const int* __restrict__ mask,
                                            const float* __restrict__ smask,
                                            f16* __restrict__ p)
{
    const int lt = LT_TAB[blockIdx.x], mt = MT_TAB[blockIdx.x], b = blockIdx.y;
    __shared__ f16 lds[(BM + BN) * BK];
    f32x4 acc[4][4];
    const size_t boff = (size_t)b * LEN * HID;
    gemm_core(q + boff + (size_t)lt * BM * HID, HID,
              kmat + boff + (size_t)mt * BN * HID, HID,
              HID / BK, lds, lds + BM * BK, acc);
    f16 vals[4][4][4];
    {
        EPILOGUE_IDX();
        #pragma unroll
        for (int r = 0; r < 4; ++r)
            #pragma unroll
            for (int c = 0; c < 4; ++c) {
                const int m = mt * BN + wc * 64 + c * 16 + c0;
                const int keepcol = mask[b * LEN + m];
                #pragma unroll
                for (int i = 0; i < 4; ++i) {
                    const int l = lt * BM + wr * 64 + r * 16 + r0 + i;
                    const bool keep = (l == m) || ((m <= l) && (keepcol != 0));
                    float v = keep ? acc[r][c][i] * smask[l * LEN + m] : 0.f;
                    v = fmaxf(v, 0.f);
                    vals[r][c][i] = (f16)(v * v);
                }
            }
    }
    store_tile_f16(lds, vals, p + (size_t)b * LEN * LEN + (size_t)lt * BM * LEN + mt * BN, LEN);
}

// ---- batched p@v (vt) -> out f32, causal K truncation; long blocks dispatch first ----
__global__ __launch_bounds__(256) void k_pv(const f16* __restrict__ p,
                                            const f16* __restrict__ vt,
                                            float* __restrict__ out)
{
    const int ht = blockIdx.x, lt = 3 - blockIdx.y, b = blockIdx.z;
    __shared__ f16 lds[(BM + BN) * BK];
    f32x4 acc[4][4];
    gemm_core(p + (size_t)b * LEN * LEN + (size_t)lt * BM * LEN, LEN,
              vt + (size_t)b * HID * LEN + (size_t)ht * BN * LEN, LEN,
              (lt + 1) * BM / BK, lds, lds + BM * BK, acc);
    EPILOGUE_IDX();
    // undo q,k 2^10 lifts (squared -> 2^40) and /(L*H)=2^18 : 2^-58 exact
    const float SCALE = 3.4694469519536142e-18f;
    #pragma unroll
    for (int r = 0; r < 4; ++r)
        #pragma unroll
        for (int c = 0; c < 4; ++c) {
            const int h = ht * BN + wc * 64 + c * 16 + c0;
            #pragma unroll
            for (int i = 0; i < 4; ++i) {
                const int l = lt * BM + wr * 64 + r * 16 + r0 + i;
                out[(size_t)b * LEN * HID + (size_t)l * HID + h] = acc[r][c][i] * SCALE;
            }
        }
}

// ---- one prep launch: gather(x) + 4x weight f2h + smask ----
__global__ __launch_bounds__(256) void k_prep(const int* __restrict__ pos,
                                              const float* __restrict__ item_emb,
                                              const float* __restrict__ pos_emb,
                                              f16* __restrict__ x,
                                              const float* __restrict__ Wz,
                                              const float* __restrict__ Wv,
                                              const float* __restrict__ Wq,
                                              const float* __restrict__ Wk,
                                              f16* __restrict__ Wzh,
                                              f16* __restrict__ Wvh,
                                              f16* __restrict__ Wqh,
                                              f16* __restrict__ Wkh,
                                              const float* __restrict__ sw,
                                              const float* __restrict__ gum,
                                              float* __restrict__ smask)
{
    const int bid = blockIdx.x;
    const int tid = threadIdx.x;
    if (bid < 16384) {                       // gather: x = item_emb[pos] + pos_emb
        const int t = bid * 256 + tid;
        const int i = t >> 7;
        const int c = t & 127;
        const int l = i & (LEN - 1);
        const int item = pos[i];
        const float4 a  = ((const float4*)(item_emb + (size_t)item * HID))[c];
        const float4 b4 = ((const float4*)(pos_emb + (size_t)l * HID))[c];
        f16x4 o = { (f16)(a.x + b4.x), (f16)(a.y + b4.y),
                    (f16)(a.z + b4.z), (f16)(a.w + b4.w) };
        *(f16x4*)(x + (size_t)t * 4) = o;
    } else if (bid < 16384 + 1024) {         // weight f32 -> f16
        const int r = bid - 16384;
        const int w = r >> 8;
        const float* s = (w == 0) ? Wz : (w == 1) ? Wv : (w == 2) ? Wq : Wk;
        f16* d = (w == 0) ? Wzh : (w == 1) ? Wvh : (w == 2) ? Wqh : Wkh;
        const int t = (r & 255) * 256 + tid;
        const float4 v = ((const float4*)s)[t];
        f16x4 o = { (f16)v.x, (f16)v.y, (f16)v.z, (f16)v.w };
        *(f16x4*)(d + (size_t)t * 4) = o;
    } else {                                 // gumbel-sigmoid smask (fp32)
        const int t = (bid - 16384 - 1024) * 256 + tid;
        const float4 w4 = ((const float4*)sw)[t];
        const float4 g4 = ((const float4*)gum)[t];
        float4 o;
        o.x = 1.f / (1.f + expf(-(logf(w4.x / (1.f - w4.x)) + g4.x) * 5.f));
        o.y = 1.f / (1.f + expf(-(logf(w4.y / (1.f - w4.y)) + g4.y) * 5.f));
        o.z = 1.f / (1.f + expf(-(logf(w4.z / (1.f - w4.z)) + g4.z) * 5.f));
        o.w = 1.f / (1.f + expf(-(logf(w4.w / (1.f - w4.w)) + g4.w) * 5.f));
        ((float4*)smask)[t] = o;
    }
}

extern "C" void kernel_launch(void* const* d_in, const int* in_sizes, int n_in,
                              void* d_out, int out_size, void* d_ws, size_t ws_size,
                              hipStream_t stream)
{
    const int*   positives = (const int*)  d_in[0];
    const int*   mask      = (const int*)  d_in[1];
    const float* item_emb  = (const float*)d_in[2];
    const float* pos_emb   = (const float*)d_in[3];
    const float* Wz        = (const float*)d_in[4];
    const float* Wv        = (const float*)d_in[5];
    const float* Wq        = (const float*)d_in[6];
    const float* Wk        = (const float*)d_in[7];
    const float* gamma_q   = (const float*)d_in[8];
    const float* beta_q    = (const float*)d_in[9];
    const float* gamma_k   = (const float*)d_in[10];
    const float* beta_k    = (const float*)d_in[11];
    const float* sparse_w  = (const float*)d_in[12];
    const float* gumbel    = (const float*)d_in[13];
    float* out = (float*)d_out;

    char* ws = (char*)d_ws;
    const size_t BUFB = (size_t)BATCH * LEN * HID * sizeof(f16);  // 32 MB
    f16* buf0 = (f16*)ws;                // x  -> p
    f16* buf1 = (f16*)(ws + BUFB);       // z
    f16* buf2 = (f16*)(ws + 2 * BUFB);   // vt
    f16* Wzh  = (f16*)(ws + 3 * BUFB);
    f16* Wvh  = Wzh + LEN * HID;
    f16* Wqh  = Wvh + LEN * HID;
    f16* Wkh  = Wqh + LEN * HID;
    float* smask = (float*)(Wkh + LEN * HID);
    // q,k live in d_out (exactly 2 x 32MB fp16) until k_pv overwrites it
    f16* qh = (f16*)d_out;
    f16* kh = qh + (size_t)BATCH * LEN * HID;

    k_prep<<<16384 + 1024 + 256, 256, 0, stream>>>(
        positives, item_emb, pos_emb, buf0,
        Wz, Wv, Wq, Wk, Wzh, Wvh, Wqh, Wkh,
        sparse_w, gumbel, smask);

    k_zg<<<dim3(HID / BN, (BATCH * LEN) / BM), 256, 0, stream>>>(buf0, Wzh, buf1);

    k_vqk<<<3072, 256, 0, stream>>>(buf0, buf1, Wvh, Wqh, Wkh,
                                    gamma_q, beta_q, gamma_k, beta_k,
                                    buf2, qh, kh);

    k_qk<<<dim3(10, 64), 256, 0, stream>>>(qh, kh, mask, smask, buf0);

    k_pv<<<dim3(4, 4, BATCH), 256, 0, stream>>>(buf0, buf2, out);
}